// Round 1
// baseline (439.692 us; speedup 1.0000x reference)
//
#include <hip/hip_runtime.h>
#include <math.h>

#define BB 16
#define TT 512
#define VV 8000
#define BLANK 0
#define LSM 0.1f
#define W_SOFT 0.5f
#define BLOCK 256

// Kernel 0: per-batch run scan -> meta[b*T+t] = (nonblank ? label_id : -1),
// inv_nexists[b] = 1/count(nonblank). Also zeroes d_out (re-poisoned each replay).
__global__ __launch_bounds__(TT) void meta_kernel(
    const int* __restrict__ aligns,
    const int* __restrict__ xlens,
    int* __restrict__ meta,
    float* __restrict__ inv_nexists,
    float* __restrict__ out) {
  int b = blockIdx.x;
  int t = threadIdx.x;  // 512 threads, one per frame
  if (b == 0 && t == 0) out[0] = 0.0f;

  __shared__ int s[TT];
  int xlen = xlens[b];
  int a  = (t < xlen) ? aligns[b * TT + t] : BLANK;
  int ap = BLANK;
  if (t > 0) ap = ((t - 1) < xlen) ? aligns[b * TT + t - 1] : BLANK;
  int nonblank = (a != BLANK) ? 1 : 0;
  int runstart = (nonblank && (a != ap)) ? 1 : 0;

  // inclusive Hillis-Steele scan of runstart flags
  s[t] = runstart;
  __syncthreads();
  for (int off = 1; off < TT; off <<= 1) {
    int v = (t >= off) ? s[t - off] : 0;
    __syncthreads();
    s[t] += v;
    __syncthreads();
  }
  int label_id = s[t] - 1;             // >=0 whenever nonblank
  meta[b * TT + t] = nonblank ? label_id : -1;
  __syncthreads();

  // count nonblank frames
  s[t] = nonblank;
  __syncthreads();
  for (int off = TT / 2; off > 0; off >>= 1) {
    if (t < off) s[t] += s[t + off];
    __syncthreads();
  }
  if (t == 0) inv_nexists[b] = 1.0f / (float)s[0];
}

// Kernel 1: one block per (b,t) frame; blanks exit immediately.
__global__ __launch_bounds__(BLOCK) void frame_kernel(
    const float* __restrict__ logits,
    const int* __restrict__ ys,
    const float* __restrict__ soft,
    const int* __restrict__ meta,
    const float* __restrict__ inv_nexists,
    float* __restrict__ out) {
  int idx = blockIdx.x;
  int lm = meta[idx];
  if (lm < 0) return;
  int b = idx / TT;

  __shared__ float xs[VV];      // 32000 B: staged logits row
  __shared__ float red[8];

  const float* xrow = logits + (size_t)idx * VV;
  const float* srow = soft + ((size_t)(b * TT + lm)) * VV;
  int tid = threadIdx.x;
  int wid = tid >> 6;

  // Phase A: global -> LDS (float4), fused max + sum
  float tmax = -INFINITY, tsum = 0.0f;
  for (int i = tid * 4; i < VV; i += BLOCK * 4) {
    float4 x = *(const float4*)(xrow + i);
    *(float4*)(xs + i) = x;
    tmax = fmaxf(tmax, fmaxf(fmaxf(x.x, x.y), fmaxf(x.z, x.w)));
    tsum += (x.x + x.y) + (x.z + x.w);
  }
  for (int off = 32; off > 0; off >>= 1) {
    tmax = fmaxf(tmax, __shfl_xor(tmax, off));
    tsum += __shfl_xor(tsum, off);
  }
  if ((tid & 63) == 0) { red[wid] = tmax; red[4 + wid] = tsum; }
  __syncthreads();
  float bmax = fmaxf(fmaxf(red[0], red[1]), fmaxf(red[2], red[3]));
  float bsum = (red[4] + red[5]) + (red[6] + red[7]);
  __syncthreads();

  // Phase B: sumexp from LDS
  float tse = 0.0f;
  for (int i = tid * 4; i < VV; i += BLOCK * 4) {
    float4 x = *(const float4*)(xs + i);
    tse += __expf(x.x - bmax) + __expf(x.y - bmax) +
           __expf(x.z - bmax) + __expf(x.w - bmax);
  }
  for (int off = 32; off > 0; off >>= 1) tse += __shfl_xor(tse, off);
  if ((tid & 63) == 0) red[wid] = tse;
  __syncthreads();
  float sumexp = (red[0] + red[1]) + (red[2] + red[3]);
  float C = bmax + logf(sumexp);   // logZ: logp[v] = x[v] - C
  __syncthreads();

  // Phase C: dot(soft_row, x - C), streaming soft row once
  float tdot = 0.0f;
  for (int i = tid * 4; i < VV; i += BLOCK * 4) {
    float4 sv = *(const float4*)(srow + i);
    float4 x = *(const float4*)(xs + i);
    tdot += sv.x * (x.x - C) + sv.y * (x.y - C) +
            sv.z * (x.z - C) + sv.w * (x.w - C);
  }
  for (int off = 32; off > 0; off >>= 1) tdot += __shfl_xor(tdot, off);
  if ((tid & 63) == 0) red[wid] = tdot;
  __syncthreads();

  if (tid == 0) {
    float dot = (red[0] + red[1]) + (red[2] + red[3]);
    int y = ys[b * TT + lm];
    float logp_y = xs[y] - C;
    float sum_lp = bsum - (float)VV * C;
    float frame_hard = (1.0f - LSM) * logp_y +
                       (LSM / (float)(VV - 1)) * (sum_lp - logp_y);
    float val = W_SOFT * dot + (1.0f - W_SOFT) * frame_hard;
    atomicAdd(out, -val * inv_nexists[b] * (1.0f / (float)BB));
  }
}

extern "C" void kernel_launch(void* const* d_in, const int* in_sizes, int n_in,
                              void* d_out, int out_size, void* d_ws, size_t ws_size,
                              hipStream_t stream) {
  const float* logits = (const float*)d_in[0];
  const int*   ys     = (const int*)d_in[1];
  const float* soft   = (const float*)d_in[2];
  const int*   aligns = (const int*)d_in[3];
  const int*   xlens  = (const int*)d_in[4];
  // d_in[5] = ylens: unused by the reference math

  int*   meta  = (int*)d_ws;
  float* inv_n = (float*)((char*)d_ws + (size_t)BB * TT * sizeof(int));
  float* out   = (float*)d_out;

  meta_kernel<<<BB, TT, 0, stream>>>(aligns, xlens, meta, inv_n, out);
  frame_kernel<<<BB * TT, BLOCK, 0, stream>>>(logits, ys, soft, meta, inv_n, out);
}